// Round 7
// baseline (358.585 us; speedup 1.0000x reference)
//
#include <hip/hip_runtime.h>
#include <hip/hip_fp16.h>

typedef _Float16 half4v __attribute__((ext_vector_type(4)));
typedef _Float16 half8v __attribute__((ext_vector_type(8)));
typedef float floatx4 __attribute__((ext_vector_type(4)));

#define GLOBAL_AS __attribute__((address_space(1)))
#define LDS_AS __attribute__((address_space(3)))

// async 16B/lane global->LDS DMA; lds dest = wave-uniform base + lane*16
__device__ __forceinline__ void async_copy16(const _Float16* g, _Float16* l) {
    __builtin_amdgcn_global_load_lds((const GLOBAL_AS unsigned int*)g,
                                     (LDS_AS unsigned int*)l, 16, 0, 0);
}

// ---------------- fused preprocessing: converts + 3 transposes, one launch --------
__device__ __forceinline__ void transpose_tile(const float* __restrict__ in,
                                               _Float16* __restrict__ out,
                                               int R, int C, int bx, int by,
                                               float* tile /*[32][33]*/) {
    int tx = threadIdx.x & 31, ty = threadIdx.x >> 5;  // 32x8
    int bc = bx * 32, br = by * 32;
#pragma unroll
    for (int i = 0; i < 32; i += 8)
        tile[(ty + i) * 33 + tx] = in[(size_t)(br + ty + i) * C + bc + tx];
    __syncthreads();
#pragma unroll
    for (int i = 0; i < 32; i += 8)
        out[(size_t)(bc + ty + i) * R + br + tx] = (_Float16)tile[tx * 33 + ty + i];
}

__global__ __launch_bounds__(256) void k_preproc(const float* __restrict__ x,
                                                 _Float16* __restrict__ xh,
                                                 const float* __restrict__ q,
                                                 _Float16* __restrict__ qh,
                                                 const float* __restrict__ Wk,
                                                 _Float16* __restrict__ wkT,
                                                 const float* __restrict__ Wq,
                                                 _Float16* __restrict__ wqT,
                                                 const float* __restrict__ y,
                                                 _Float16* __restrict__ yT) {
    __shared__ float tile[32 * 33];
    const int b = blockIdx.x;
    if (b < 12288) {
        const int na = 8192 * 1024;
        int i = (b * 256 + threadIdx.x) * 4;
        const float* src;
        _Float16* dst;
        if (i < na) { src = x + i; dst = xh + i; }
        else        { src = q + (i - na); dst = qh + (i - na); }
        float4 v = *(const float4*)src;
        half4v h;
        h[0] = (_Float16)v.x; h[1] = (_Float16)v.y;
        h[2] = (_Float16)v.z; h[3] = (_Float16)v.w;
        *(half4v*)dst = h;
    } else if (b < 12800) {
        const int idx = b - 12288;
        transpose_tile(Wk, wkT, 1024, 512, idx & 15, idx >> 4, tile);
    } else if (b < 13312) {
        const int idx = b - 12800;
        transpose_tile(Wq, wqT, 1024, 512, idx & 15, idx >> 4, tile);
    } else {
        const int idx = b - 13312;
        transpose_tile(y, yT, 8192, 256, idx & 7, idx >> 3, tile);
    }
}

// ---------------- NT GEMM (m97-structure): C = scale * A @ B^T ----------------
// 128x128 tile, BK=64, 4 waves. Proven kernel; used for projections and PV.
template <int OUT_MODE>
__global__ __launch_bounds__(256) void k_gemm_nt(const _Float16* __restrict__ A,
                                                 const _Float16* __restrict__ B,
                                                 void* __restrict__ C,
                                                 const _Float16* __restrict__ A2,
                                                 const _Float16* __restrict__ B2,
                                                 void* __restrict__ C2,
                                                 int M, int N, int K, int kChunk,
                                                 float scale, float scale2) {
    __shared__ __align__(16) _Float16 As[128 * 64];
    __shared__ __align__(16) _Float16 Bs[128 * 64];
    const int tid  = threadIdx.x;
    const int lane = tid & 63;
    const int wave = tid >> 6;
    const int wm   = (wave >> 1) * 64;
    const int wn   = (wave & 1) * 64;
    const int quad = lane >> 4;
    const int lr   = lane & 15;

    int by = blockIdx.y;
    if (OUT_MODE == 3 && by >= 64) {
        by -= 64;
        A = A2; B = B2; C = C2; scale = scale2;
    }
    const long m0 = (long)by * 128;
    const long n0 = (long)blockIdx.x * 128;
    const int kBegin = blockIdx.z * kChunk;
    const int kEnd   = kBegin + kChunk;

    floatx4 acc[4][4] = {};

    const int rl = lane >> 3;
    const int gc = (lane & 7) ^ rl;
    const long arow = m0 + wave * 32 + rl;
    const long brow = n0 + wave * 32 + rl;

    for (int kt = kBegin; kt < kEnd; kt += 64) {
        const _Float16* Ap = A + arow * (long)K + kt + gc * 8;
        const _Float16* Bp = B + brow * (long)K + kt + gc * 8;
        _Float16* Al = &As[(wave * 32) * 64];
        _Float16* Bl = &Bs[(wave * 32) * 64];
#pragma unroll
        for (int i = 0; i < 4; ++i) {
            async_copy16(Ap + (long)(i * 8) * K, Al + i * 8 * 64);
            async_copy16(Bp + (long)(i * 8) * K, Bl + i * 8 * 64);
        }
        __syncthreads();

#pragma unroll
        for (int kk = 0; kk < 64; kk += 32) {
            half8v af[4], bf[4];
            const int cg = (kk >> 3) + quad;
            const int sl = (cg ^ (lr & 7)) * 8;
#pragma unroll
            for (int i = 0; i < 4; ++i)
                af[i] = *(const half8v*)&As[(wm + i * 16 + lr) * 64 + sl];
#pragma unroll
            for (int j = 0; j < 4; ++j)
                bf[j] = *(const half8v*)&Bs[(wn + j * 16 + lr) * 64 + sl];
#pragma unroll
            for (int i = 0; i < 4; ++i)
#pragma unroll
                for (int j = 0; j < 4; ++j)
                    acc[i][j] = __builtin_amdgcn_mfma_f32_16x16x32_f16(af[i], bf[j], acc[i][j], 0, 0, 0);
        }
        __syncthreads();
    }

#pragma unroll
    for (int i = 0; i < 4; ++i) {
        long rbase = m0 + wm + i * 16 + quad * 4;
#pragma unroll
        for (int j = 0; j < 4; ++j) {
            long col = n0 + wn + j * 16 + lr;
#pragma unroll
            for (int r = 0; r < 4; ++r) {
                float val = acc[i][j][r] * scale;
                if (OUT_MODE == 1)
                    ((float*)C)[(size_t)blockIdx.z * M * N + (rbase + r) * (long)N + col] = val;
                else
                    ((_Float16*)C)[(rbase + r) * (long)N + col] = (_Float16)val;
            }
        }
    }
}

// ---------------- 8-phase 256x256 NT GEMM for logits ----------------
// C[M,N] = A[M,K] @ B[N,K]^T, f16 out. 512 threads = 8 waves (wm=wave>>2,
// wn=wave&3), per-wave output 128x64 split into 4 quadrants (qa,qb):
//   rows = qa*128 + wm*64 + fi*16, cols = qb*128 + wn*32 + fj*16
// so quadrant (qa,qb) of ALL waves touches exactly A-half qa and B-half qb.
// 2 LDS buffers (128 KiB, 1 block/CU). Per K-tile: 4 phases, each stages one
// half-tile of tile t+1 (order Ah0,Bh0,Bh1,Ah1) and computes one quadrant of
// tile t. Counted s_waitcnt vmcnt(6) at p0/p1/p2 guarantees exactly the halves
// that phase reads (2 loads/phase/thread; queue arithmetic verified), with >=3
// phases of latency slack -- loads stay in flight across barriers (T3/T4).
// Raw s_barrier + sched_barrier(0) (no vmcnt(0) drain); setprio around MFMA
// (T5). Chunk-XOR swizzle identical to k_gemm_nt (bank-conflict-free, proven).
#define UNROLL _Pragma("unroll")

#define LOAD_AF(QA)                                                            \
    UNROLL for (int fi = 0; fi < 4; ++fi)                                      \
    UNROLL for (int s = 0; s < 2; ++s)                                         \
        af[fi][s] = *(const half8v*)&As[buf][((QA) * 128 + wm * 64 + fi * 16 + lr) * 64 + \
                                            (((s * 4 + quad) ^ (lr & 7)) * 8)];

#define LOAD_BF(DST, QB)                                                       \
    UNROLL for (int fj = 0; fj < 2; ++fj)                                      \
    UNROLL for (int s = 0; s < 2; ++s)                                         \
        DST[fj][s] = *(const half8v*)&Bs[buf][((QB) * 128 + wn * 32 + fj * 16 + lr) * 64 + \
                                             (((s * 4 + quad) ^ (lr & 7)) * 8)];

#define MFMA_Q(QA, QB, BF)                                                     \
    __builtin_amdgcn_s_setprio(1);                                             \
    UNROLL for (int fi = 0; fi < 4; ++fi)                                      \
    UNROLL for (int fj = 0; fj < 2; ++fj)                                      \
    UNROLL for (int s = 0; s < 2; ++s)                                         \
        acc[QA][fi][QB][fj] = __builtin_amdgcn_mfma_f32_16x16x32_f16(          \
            af[fi][s], (BF)[fj][s], acc[QA][fi][QB][fj], 0, 0, 0);             \
    __builtin_amdgcn_s_setprio(0);

#define BAR()                                                                  \
    __builtin_amdgcn_s_barrier();                                              \
    __builtin_amdgcn_sched_barrier(0);

__global__ __launch_bounds__(512, 2) void k_gemm_8p(const _Float16* __restrict__ A,
                                                    const _Float16* __restrict__ B,
                                                    _Float16* __restrict__ C,
                                                    int M, int N, int K) {
    __shared__ __align__(16) _Float16 As[2][256 * 64];
    __shared__ __align__(16) _Float16 Bs[2][256 * 64];
    const int tid  = threadIdx.x;
    const int lane = tid & 63;
    const int wave = tid >> 6;   // 0..7
    const int wm   = wave >> 2;  // 0..1
    const int wn   = wave & 3;   // 0..3
    const int quad = lane >> 4;
    const int lr   = lane & 15;
    const long m0 = (long)blockIdx.y * 256;
    const long n0 = (long)blockIdx.x * 256;

    // stager: one half-tile = 128 rows x 64 cols f16 = 2 calls; call covers 64
    // rows (row = h*128 + c*64 + tid>>3, chunk = (tid&7)^((tid>>3)&7)); per-wave
    // LDS base advances by 8 rows -- matches DMA base+lane*16 with the XOR
    // swizzle rule slot = chunk ^ (row&7).
    const int gchunk = (tid & 7) ^ ((tid >> 3) & 7);
    auto stage_half = [&](const _Float16* __restrict__ G, _Float16* __restrict__ Sb,
                          long r0, int h, int kt) {
#pragma unroll
        for (int c = 0; c < 2; ++c) {
            const int rb = h * 128 + c * 64;
            const _Float16* g = G + (r0 + rb + (tid >> 3)) * (long)K + kt + gchunk * 8;
            async_copy16(g, Sb + (rb + wave * 8) * 64);
        }
    };

    floatx4 acc[2][4][2][2] = {};
    half8v af[4][2], bf0[2][2], bf1[2][2];

    const int NT = K / 64;
    // prologue: stage tile 0, order Ah0, Bh0, Bh1, Ah1 (matches steady state)
    stage_half(A, &As[0][0], m0, 0, 0);
    stage_half(B, &Bs[0][0], n0, 0, 0);
    stage_half(B, &Bs[0][0], n0, 1, 0);
    stage_half(A, &As[0][0], m0, 1, 0);

    int buf = 0;
    for (int t = 0; t < NT - 1; ++t) {
        const int nb = buf ^ 1;
        const int ktn = (t + 1) * 64;
        _Float16* Anext = &As[nb][0];
        _Float16* Bnext = &Bs[nb][0];
        // ---- p0: stage t+1.Ah0; compute q(0,0) [needs t.Ah0 + t.Bh0]
        stage_half(A, Anext, m0, 0, ktn);
        asm volatile("s_waitcnt vmcnt(6)" ::: "memory");  // t.Ah0,t.Bh0 done
        BAR();
        LOAD_AF(0);
        LOAD_BF(bf0, 0);
        MFMA_Q(0, 0, bf0);
        BAR();
        // ---- p1: stage t+1.Bh0; compute q(0,1) [needs t.Bh1]
        stage_half(B, Bnext, n0, 0, ktn);
        asm volatile("s_waitcnt vmcnt(6)" ::: "memory");  // + t.Bh1 done
        BAR();
        LOAD_BF(bf1, 1);
        MFMA_Q(0, 1, bf1);
        BAR();
        // ---- p2: stage t+1.Bh1; compute q(1,0) [needs t.Ah1]
        stage_half(B, Bnext, n0, 1, ktn);
        asm volatile("s_waitcnt vmcnt(6)" ::: "memory");  // + t.Ah1 done
        BAR();
        LOAD_AF(1);
        MFMA_Q(1, 0, bf0);
        BAR();
        // ---- p3: stage t+1.Ah1; compute q(1,1) [no new deps]
        stage_half(A, Anext, m0, 1, ktn);
        BAR();
        MFMA_Q(1, 1, bf1);
        BAR();
        buf = nb;
    }
    // ---- last tile: no stages; drain waits 4/2/0
    asm volatile("s_waitcnt vmcnt(4)" ::: "memory");
    BAR();
    LOAD_AF(0);
    LOAD_BF(bf0, 0);
    MFMA_Q(0, 0, bf0);
    BAR();
    asm volatile("s_waitcnt vmcnt(2)" ::: "memory");
    BAR();
    LOAD_BF(bf1, 1);
    MFMA_Q(0, 1, bf1);
    BAR();
    asm volatile("s_waitcnt vmcnt(0)" ::: "memory");
    BAR();
    LOAD_AF(1);
    MFMA_Q(1, 0, bf0);
    BAR();
    MFMA_Q(1, 1, bf1);

    // epilogue: C/D layout col = lane&15, row = quad*4 + reg
#pragma unroll
    for (int qa = 0; qa < 2; ++qa)
#pragma unroll
    for (int fi = 0; fi < 4; ++fi) {
        const long rbase = m0 + qa * 128 + wm * 64 + fi * 16 + quad * 4;
#pragma unroll
        for (int qb = 0; qb < 2; ++qb)
#pragma unroll
        for (int fj = 0; fj < 2; ++fj) {
            const long col = n0 + qb * 128 + wn * 32 + fj * 16 + lr;
#pragma unroll
            for (int r = 0; r < 4; ++r)
                C[(rbase + r) * (long)N + col] = (_Float16)acc[qa][fi][qb][fj][r];
        }
    }
}

// ---------------- sum Z fp32 partials [Z][n] -> out[n] ----------------
template <int Z>
__global__ __launch_bounds__(256) void k_reduce(const float* __restrict__ part,
                                                float* __restrict__ out, int n) {
    int i = (blockIdx.x * 256 + threadIdx.x) * 4;
    if (i >= n) return;
    float4 s = *(const float4*)(part + i);
#pragma unroll
    for (int z = 1; z < Z; ++z) {
        float4 v = *(const float4*)(part + (size_t)z * n + i);
        s.x += v.x; s.y += v.y; s.z += v.z; s.w += v.w;
    }
    *(float4*)(out + i) = s;
}

// ---------------- masked softmax, in-place on f16 logits [4096][8192] ----------------
__global__ __launch_bounds__(256) void k_softmax(_Float16* __restrict__ logits,
                                                 const int* __restrict__ mask) {
    const int q   = blockIdx.x;
    const int tid = threadIdx.x;
    _Float16* row   = logits + (size_t)q * 8192;
    const int* mrow = mask + (size_t)q * 8192;

    float v[32];
    unsigned mb = 0;
    float lmax = -3.0e38f;
#pragma unroll
    for (int i = 0; i < 8; ++i) {
        int base = i * 1024 + tid * 4;
        int4 mm  = *(const int4*)(mrow + base);
        half4v h = *(const half4v*)(row + base);
#pragma unroll
        for (int j = 0; j < 4; ++j) v[i * 4 + j] = (float)h[j];
        if (mm.x > 0) { mb |= 1u << (i * 4 + 0); lmax = fmaxf(lmax, v[i * 4 + 0]); }
        if (mm.y > 0) { mb |= 1u << (i * 4 + 1); lmax = fmaxf(lmax, v[i * 4 + 1]); }
        if (mm.z > 0) { mb |= 1u << (i * 4 + 2); lmax = fmaxf(lmax, v[i * 4 + 2]); }
        if (mm.w > 0) { mb |= 1u << (i * 4 + 3); lmax = fmaxf(lmax, v[i * 4 + 3]); }
    }
#pragma unroll
    for (int off = 32; off > 0; off >>= 1) lmax = fmaxf(lmax, __shfl_xor(lmax, off, 64));
    __shared__ float redmax[4], redsum[4];
    if ((tid & 63) == 0) redmax[tid >> 6] = lmax;
    __syncthreads();
    lmax = fmaxf(fmaxf(redmax[0], redmax[1]), fmaxf(redmax[2], redmax[3]));

    float lsum = 0.f;
#pragma unroll
    for (int i = 0; i < 32; ++i) {
        float e = ((mb >> i) & 1u) ? __expf(v[i] - lmax) : 0.f;
        v[i] = e;
        lsum += e;
    }
#pragma unroll
    for (int off = 32; off > 0; off >>= 1) lsum += __shfl_xor(lsum, off, 64);
    if ((tid & 63) == 0) redsum[tid >> 6] = lsum;
    __syncthreads();
    lsum = redsum[0] + redsum[1] + redsum[2] + redsum[3];
    float inv = lsum > 0.f ? 1.f / lsum : 0.f;

#pragma unroll
    for (int i = 0; i < 8; ++i) {
        int base = i * 1024 + tid * 4;
        half4v h;
#pragma unroll
        for (int j = 0; j < 4; ++j) h[j] = (_Float16)(v[i * 4 + j] * inv);
        *(half4v*)(row + base) = h;
    }
}

extern "C" void kernel_launch(void* const* d_in, const int* in_sizes, int n_in,
                              void* d_out, int out_size, void* d_ws, size_t ws_size,
                              hipStream_t stream) {
    const float* search_x = (const float*)d_in[0];  // [8192,1024]
    const float* search_y = (const float*)d_in[1];  // [8192,256]
    const float* query_x  = (const float*)d_in[2];  // [4096,1024]
    const int*   mask     = (const int*)d_in[3];    // [4096,8192]
    const float* Wk       = (const float*)d_in[4];  // [1024,512]
    const float* Wq       = (const float*)d_in[5];  // [1024,512]
    (void)in_sizes; (void)n_in; (void)ws_size; (void)out_size;

    char* p = (char*)d_ws;
    _Float16* xh   = (_Float16*)p; p += (size_t)8192 * 1024 * 2;  // x f16
    _Float16* qh   = (_Float16*)p; p += (size_t)4096 * 1024 * 2;  // q f16
    _Float16* wkT  = (_Float16*)p; p += (size_t)512 * 1024 * 2;   // Wk^T f16
    _Float16* wqT  = (_Float16*)p; p += (size_t)512 * 1024 * 2;   // Wq^T f16
    _Float16* yT   = (_Float16*)p; p += (size_t)256 * 8192 * 2;   // y^T f16
    _Float16* keys = (_Float16*)p; p += (size_t)8192 * 512 * 2;   // keys f16
    _Float16* qk   = (_Float16*)p; p += (size_t)4096 * 512 * 2;   // qk f16 (pre-scaled)
    _Float16* lg   = (_Float16*)p; p += (size_t)4096 * 8192 * 2;  // logits/p f16
    float*    part = (float*)p;    p += (size_t)4 * 4096 * 256 * 4; // PV split-K partials

    // all preprocessing in one launch
    k_preproc<<<15360, 256, 0, stream>>>(search_x, xh, query_x, qh,
                                         Wk, wkT, Wq, wqT, search_y, yT);

    // merged projections: keys = x @ Wk (by<64); qk = (q @ Wq)/sqrt(512) (by>=64)
    k_gemm_nt<3><<<dim3(4, 96, 1), 256, 0, stream>>>(
        xh, wkT, keys, qh, wqT, qk, 8192, 512, 1024, 1024,
        1.0f, 0.04419417382415922f);

    // logits = qk @ keys^T  (scale folded into qk) -- 8-phase 256^2 kernel
    k_gemm_8p<<<dim3(32, 16), 512, 0, stream>>>(qk, keys, lg, 4096, 8192, 512);

    // masked softmax in-place
    k_softmax<<<4096, 256, 0, stream>>>(lg, mask);

    // out = p @ y  (M=4096,N=256,K=8192), split-K=4 -> fp32 partials, reduce
    k_gemm_nt<1><<<dim3(2, 32, 4), 256, 0, stream>>>(
        lg, yT, part, nullptr, nullptr, nullptr, 4096, 256, 8192, 2048, 1.0f, 0.f);
    k_reduce<4><<<1024, 256, 0, stream>>>(part, (float*)d_out, 4096 * 256);
}